// Round 3
// baseline (298.030 us; speedup 1.0000x reference)
//
#include <hip/hip_runtime.h>

#define DEV __device__ __forceinline__

DEV float wsum64(float v) {
    v += __shfl_xor(v, 32);
    v += __shfl_xor(v, 16);
    v += __shfl_xor(v, 8);
    v += __shfl_xor(v, 4);
    v += __shfl_xor(v, 2);
    v += __shfl_xor(v, 1);
    return v;
}
DEV float wsum16(float v) {
    v += __shfl_xor(v, 8);
    v += __shfl_xor(v, 4);
    v += __shfl_xor(v, 2);
    v += __shfl_xor(v, 1);
    return v;
}
DEV float lrelu(float x, float a) { return x > 0.f ? x : a * x; }
DEV float elu1(float x) { return x > 0.f ? x : (__expf(x) - 1.f); }

// softmax-combine for a 13-node star GAT given per-lane Wh rows.
DEV void star13(const float wh[13], const float* __restrict__ a, int l,
                float& out0, float& wh0) {
    float alo = a[l], ahi = a[64 + l];
    float si0 = wsum64(wh[0] * alo);
    float e[13];
    float m = -1e30f;
#pragma unroll
    for (int r = 0; r < 13; ++r) {
        float sj = wsum64(wh[r] * ahi);
        float t = lrelu(si0 + sj, 0.2f);
        e[r] = t;
        m = fmaxf(m, t);
    }
    float den = 0.f, acc = 0.f;
#pragma unroll
    for (int r = 0; r < 13; ++r) {
        float p = __expf(e[r] - m);
        den += p;
        acc = __builtin_fmaf(p, wh[r], acc);
    }
    out0 = acc / den;
    wh0 = wh[0];
}

DEV void star9(const float wh[9], const float* __restrict__ a, int c,
               float& out0, float& wh0) {
    float alo = a[c], ahi = a[16 + c];
    float si0 = wsum16(wh[0] * alo);
    float e[9];
    float m = -1e30f;
#pragma unroll
    for (int r = 0; r < 9; ++r) {
        float sj = wsum16(wh[r] * ahi);
        float t = lrelu(si0 + sj, 0.2f);
        e[r] = t;
        m = fmaxf(m, t);
    }
    float den = 0.f, acc = 0.f;
#pragma unroll
    for (int r = 0; r < 9; ++r) {
        float p = __expf(e[r] - m);
        den += p;
        acc = __builtin_fmaf(p, wh[r], acc);
    }
    out0 = acc / den;
    wh0 = wh[0];
}

DEV float gatOutEpi(float w0, float wr, const float* __restrict__ a,
                    float nOth, int l) {
    float si0 = wsum64(w0 * a[l]);
    float sj0 = wsum64(w0 * a[64 + l]);
    float sjr = wsum64(wr * a[64 + l]);
    float e0 = lrelu(si0 + sj0, 0.2f);
    float er = lrelu(si0 + sjr, 0.2f);
    float m = fmaxf(e0, er);
    float p0 = __expf(e0 - m);
    float pr = __expf(er - m) * nOth;
    float o0 = (p0 * w0 + pr * wr) / (p0 + pr);
    return (elu1(o0) + nOth * elu1(w0)) * (1.f / (nOth + 1.f));
}

// Output GAT layer for two elements sharing one weight fetch.
DEV void gatOut2(const float* x0a, const float* xra,
                 const float* x0b, const float* xrb, int K4,
                 const float* __restrict__ W, const float* __restrict__ a,
                 float nOth, int l, float& outA, float& outB) {
    float w0a = 0.f, wra = 0.f, w0b = 0.f, wrb = 0.f;
    const float4* xa4 = (const float4*)x0a;
    const float4* ra4 = (const float4*)xra;
    const float4* xb4 = (const float4*)x0b;
    const float4* rb4 = (const float4*)xrb;
    for (int kc = 0; kc < K4; ++kc) {
        int k = kc * 4;
        float wk0 = W[(k + 0) * 64 + l];
        float wk1 = W[(k + 1) * 64 + l];
        float wk2 = W[(k + 2) * 64 + l];
        float wk3 = W[(k + 3) * 64 + l];
        float4 xv = xa4[kc], rv = ra4[kc];
        w0a = __builtin_fmaf(xv.x, wk0, w0a);
        w0a = __builtin_fmaf(xv.y, wk1, w0a);
        w0a = __builtin_fmaf(xv.z, wk2, w0a);
        w0a = __builtin_fmaf(xv.w, wk3, w0a);
        wra = __builtin_fmaf(rv.x, wk0, wra);
        wra = __builtin_fmaf(rv.y, wk1, wra);
        wra = __builtin_fmaf(rv.z, wk2, wra);
        wra = __builtin_fmaf(rv.w, wk3, wra);
        float4 xw = xb4[kc], rw = rb4[kc];
        w0b = __builtin_fmaf(xw.x, wk0, w0b);
        w0b = __builtin_fmaf(xw.y, wk1, w0b);
        w0b = __builtin_fmaf(xw.z, wk2, w0b);
        w0b = __builtin_fmaf(xw.w, wk3, w0b);
        wrb = __builtin_fmaf(rw.x, wk0, wrb);
        wrb = __builtin_fmaf(rw.y, wk1, wrb);
        wrb = __builtin_fmaf(rw.z, wk2, wrb);
        wrb = __builtin_fmaf(rw.w, wk3, wrb);
    }
    outA = gatOutEpi(w0a, wra, a, nOth, l);
    outB = gatOutEpi(w0b, wrb, a, nOth, l);
}

// Per-element LDS region layout (floats), total 1504 (=6016B, 16B aligned):
//  [0..832)    E1 (13x64)  -> after phase2 reused as:
//                x0s[0..128) xrs[128..256) comb[256..464) h1l[464..528)
//                hm[528..592) xc0[592..624) xcr[624..656)
//  [832..1248) hist 13x16 padded -> hsh (13x32)
//  [1248..1432) curs (184)
//  [1432..1504) hc (9x8 padded)
#define ELEM_F 1504

__global__ __launch_bounds__(128, 3) void pred_kernel(
    const float* __restrict__ obs,
    const float* __restrict__ W_se, const float* __restrict__ b_se,
    const float* __restrict__ W_de, const float* __restrict__ b_de,
    const float* __restrict__ Wh1, const float* __restrict__ ah1,
    const float* __restrict__ Wh2, const float* __restrict__ ah2,
    const float* __restrict__ Who, const float* __restrict__ aho,
    const float* __restrict__ Wc1, const float* __restrict__ ac1,
    const float* __restrict__ Wc2, const float* __restrict__ ac2,
    const float* __restrict__ Wco, const float* __restrict__ aco,
    const float* __restrict__ Wl1, const float* __restrict__ bl1,
    const float* __restrict__ Wl2, const float* __restrict__ bl2,
    const float* __restrict__ Wm1, const float* __restrict__ bm1,
    const float* __restrict__ Wm2, const float* __restrict__ bm2,
    float* __restrict__ out)
{
    const int l = threadIdx.x & 63;       // lane = channel
    const int w = threadIdx.x >> 6;       // wave in block
    const int b0 = blockIdx.x * 4 + w * 2;

    __shared__ float lds[4 * ELEM_F];
    float* S[2] = { lds + (w * 2 + 0) * ELEM_F, lds + (w * 2 + 1) * ELEM_F };

    // ---- phase 0: gather (wave-private; NO barriers anywhere) ----
#pragma unroll
    for (int e = 0; e < 2; ++e) {
        const float* o = obs + (size_t)(b0 + e) * 2064;
        float* H = S[e] + 832;
        float* curs = S[e] + 1248;
        for (int i = l; i < 208; i += 64) {
            int r = i >> 4, f = i & 15;
            float v = 0.f;
            if (f < 15) {
                int t = f / 3 + 1, ff = f % 3;
                int col = (r == 0) ? (234 + ff) : ((r - 1) * 6 + ff);
                v = o[t * 344 + col];
            }
            H[i] = v;
        }
        for (int i = l; i < 184; i += 64) curs[i] = o[1792 + i];
    }

    // ---- phase 1: 15->64 lrelu(0.1) ----
    {
        float wv[16];
#pragma unroll
        for (int k = 0; k < 15; ++k) wv[k] = W_se[k * 64 + l];
        wv[15] = 0.f;
        float bs = b_se[l];
        float acc[2][13];
#pragma unroll
        for (int e = 0; e < 2; ++e)
#pragma unroll
            for (int r = 0; r < 13; ++r) acc[e][r] = bs;
#pragma unroll
        for (int kc = 0; kc < 4; ++kc) {
#pragma unroll
            for (int e = 0; e < 2; ++e) {
                const float4* H4 = (const float4*)(S[e] + 832);
#pragma unroll
                for (int r = 0; r < 13; ++r) {
                    float4 h = H4[r * 4 + kc];
                    acc[e][r] = __builtin_fmaf(h.x, wv[kc * 4 + 0], acc[e][r]);
                    acc[e][r] = __builtin_fmaf(h.y, wv[kc * 4 + 1], acc[e][r]);
                    acc[e][r] = __builtin_fmaf(h.z, wv[kc * 4 + 2], acc[e][r]);
                    acc[e][r] = __builtin_fmaf(h.w, wv[kc * 4 + 3], acc[e][r]);
                }
            }
        }
#pragma unroll
        for (int e = 0; e < 2; ++e) {
            float* E1 = S[e];
#pragma unroll
            for (int r = 0; r < 13; ++r) E1[r * 64 + l] = lrelu(acc[e][r], 0.1f);
        }
    }
    // build cav nodes
#pragma unroll
    for (int e = 0; e < 2; ++e) {
        if (l < 54) {
            const float* curs = S[e] + 1248;
            int r = l / 6, f = l % 6;
            float v;
            if (r == 0) {
                int idx = (f < 3) ? (162 + f) : ((f == 3) ? 181 : (175 + f));
                v = curs[idx];
            } else {
                v = curs[(r - 1) * 6 + f];
            }
            (S[e] + 1432)[r * 8 + f] = v;
        }
    }

    // ---- phase 2: 64->32 linear -> hsh ----
    {
        int c = l & 31, r0 = l >> 5;
        float acc[2][7];
        float bd = b_de[c];
#pragma unroll
        for (int e = 0; e < 2; ++e)
#pragma unroll
            for (int i = 0; i < 7; ++i) acc[e][i] = bd;
        for (int kc = 0; kc < 16; ++kc) {
            int k = kc * 4;
            float w0 = W_de[(k + 0) * 32 + c];
            float w1 = W_de[(k + 1) * 32 + c];
            float w2 = W_de[(k + 2) * 32 + c];
            float w3 = W_de[(k + 3) * 32 + c];
#pragma unroll
            for (int e = 0; e < 2; ++e) {
                const float4* E4 = (const float4*)S[e];
#pragma unroll
                for (int i = 0; i < 7; ++i) {
                    int r = r0 + 2 * i;
                    float4 ev = E4[(r < 13 ? r : 0) * 16 + kc];
                    acc[e][i] = __builtin_fmaf(ev.x, w0, acc[e][i]);
                    acc[e][i] = __builtin_fmaf(ev.y, w1, acc[e][i]);
                    acc[e][i] = __builtin_fmaf(ev.z, w2, acc[e][i]);
                    acc[e][i] = __builtin_fmaf(ev.w, w3, acc[e][i]);
                }
            }
        }
#pragma unroll
        for (int e = 0; e < 2; ++e) {
            float* hsh = S[e] + 832;
#pragma unroll
            for (int i = 0; i < 7; ++i) {
                int r = r0 + 2 * i;
                if (r < 13) hsh[r * 32 + c] = acc[e][i];
            }
        }
    }

    // ---- phase 3: fused gat13 pair ----
    {
        float wh1[2][13], wh2[2][13];
#pragma unroll
        for (int e = 0; e < 2; ++e)
#pragma unroll
            for (int r = 0; r < 13; ++r) { wh1[e][r] = 0.f; wh2[e][r] = 0.f; }
#pragma unroll
        for (int kc = 0; kc < 8; ++kc) {
            int k = kc * 4;
            float a0 = Wh1[(k + 0) * 64 + l], c0 = Wh2[(k + 0) * 64 + l];
            float a1 = Wh1[(k + 1) * 64 + l], c1 = Wh2[(k + 1) * 64 + l];
            float a2 = Wh1[(k + 2) * 64 + l], c2 = Wh2[(k + 2) * 64 + l];
            float a3 = Wh1[(k + 3) * 64 + l], c3 = Wh2[(k + 3) * 64 + l];
#pragma unroll
            for (int e = 0; e < 2; ++e) {
                const float4* hs4 = (const float4*)(S[e] + 832);
#pragma unroll
                for (int r = 0; r < 13; ++r) {
                    float4 h = hs4[r * 8 + kc];
                    wh1[e][r] = __builtin_fmaf(h.x, a0, wh1[e][r]);
                    wh1[e][r] = __builtin_fmaf(h.y, a1, wh1[e][r]);
                    wh1[e][r] = __builtin_fmaf(h.z, a2, wh1[e][r]);
                    wh1[e][r] = __builtin_fmaf(h.w, a3, wh1[e][r]);
                    wh2[e][r] = __builtin_fmaf(h.x, c0, wh2[e][r]);
                    wh2[e][r] = __builtin_fmaf(h.y, c1, wh2[e][r]);
                    wh2[e][r] = __builtin_fmaf(h.z, c2, wh2[e][r]);
                    wh2[e][r] = __builtin_fmaf(h.w, c3, wh2[e][r]);
                }
            }
        }
#pragma unroll
        for (int e = 0; e < 2; ++e) {
            float o1, r1, o2, r2;
            star13(wh1[e], ah1, l, o1, r1);
            star13(wh2[e], ah2, l, o2, r2);
            float* x0s = S[e];
            float* xrs = S[e] + 128;
            x0s[l] = o1; x0s[64 + l] = o2;
            xrs[l] = r1; xrs[64 + l] = r2;
        }
    }
    // gat9 pair
    {
        int c = l & 15;
        float wc1[2][9], wc2[2][9];
#pragma unroll
        for (int e = 0; e < 2; ++e)
#pragma unroll
            for (int r = 0; r < 9; ++r) { wc1[e][r] = 0.f; wc2[e][r] = 0.f; }
#pragma unroll
        for (int k = 0; k < 6; ++k) {
            float w1 = Wc1[k * 16 + c], w2 = Wc2[k * 16 + c];
#pragma unroll
            for (int e = 0; e < 2; ++e) {
                const float* hc = S[e] + 1432;
#pragma unroll
                for (int r = 0; r < 9; ++r) {
                    float h = hc[r * 8 + k];
                    wc1[e][r] = __builtin_fmaf(h, w1, wc1[e][r]);
                    wc2[e][r] = __builtin_fmaf(h, w2, wc2[e][r]);
                }
            }
        }
#pragma unroll
        for (int e = 0; e < 2; ++e) {
            float o1, r1, o2, r2;
            star9(wc1[e], ac1, c, o1, r1);
            star9(wc2[e], ac2, c, o2, r2);
            if (l < 16) {
                float* xc0 = S[e] + 592;
                float* xcr = S[e] + 624;
                xc0[l] = o1; xc0[16 + l] = o2;
                xcr[l] = r1; xcr[16 + l] = r2;
            }
        }
    }
    // lanes layer 1
    {
        float bl = bl1[l];
        float acc[2] = { bl, bl };
        for (int kc = 0; kc < 27; ++kc) {
            int k = kc * 4;
            float w0 = Wl1[(k + 0) * 64 + l];
            float w1 = Wl1[(k + 1) * 64 + l];
            float w2 = Wl1[(k + 2) * 64 + l];
            float w3 = Wl1[(k + 3) * 64 + l];
#pragma unroll
            for (int e = 0; e < 2; ++e) {
                float4 x = ((const float4*)(S[e] + 1296))[kc];  // curs+48
                acc[e] = __builtin_fmaf(x.x, w0, acc[e]);
                acc[e] = __builtin_fmaf(x.y, w1, acc[e]);
                acc[e] = __builtin_fmaf(x.z, w2, acc[e]);
                acc[e] = __builtin_fmaf(x.w, w3, acc[e]);
            }
        }
#pragma unroll
        for (int e = 0; e < 2; ++e) (S[e] + 464)[l] = fmaxf(acc[e], 0.f);
    }
    // road gather (also zero-pads comb[205..207])
#pragma unroll
    for (int e = 0; e < 2; ++e) {
        if (l < 16) {
            float v = 0.f;
            if (l < 13) {
                int idx;
                if (l < 10) {
                    int p = l >> 1, odd = l & 1;
                    idx = ((p & 1) ? 175 : 156) + (p >> 1) * 2 + odd;
                } else {
                    idx = 169 + l;  // 179,180,181
                }
                v = (S[e] + 1248)[idx];
            }
            (S[e] + 256)[192 + l] = v;
        }
    }

    // ---- phase 4: GAT output layers + lanes2 ----
    float cv0[2], cv1[2], cv2[2];
    gatOut2(S[0], S[0] + 128, S[1], S[1] + 128, 32, Who, aho, 12.f, l,
            cv0[0], cv0[1]);
    gatOut2(S[0] + 592, S[0] + 624, S[1] + 592, S[1] + 624, 8, Wco, aco, 8.f, l,
            cv1[0], cv1[1]);
    {
        float bl = bl2[l];
        float acc[2] = { bl, bl };
        for (int kc = 0; kc < 16; ++kc) {
            int k = kc * 4;
            float w0 = Wl2[(k + 0) * 64 + l];
            float w1 = Wl2[(k + 1) * 64 + l];
            float w2 = Wl2[(k + 2) * 64 + l];
            float w3 = Wl2[(k + 3) * 64 + l];
#pragma unroll
            for (int e = 0; e < 2; ++e) {
                float4 x = ((const float4*)(S[e] + 464))[kc];
                acc[e] = __builtin_fmaf(x.x, w0, acc[e]);
                acc[e] = __builtin_fmaf(x.y, w1, acc[e]);
                acc[e] = __builtin_fmaf(x.z, w2, acc[e]);
                acc[e] = __builtin_fmaf(x.w, w3, acc[e]);
            }
        }
#pragma unroll
        for (int e = 0; e < 2; ++e) cv2[e] = fmaxf(acc[e], 0.f);
    }
#pragma unroll
    for (int e = 0; e < 2; ++e) {
        float* comb = S[e] + 256;
        comb[l] = cv0[e];
        comb[64 + l] = cv1[e];
        comb[128 + l] = cv2[e];
    }

    // ---- phase 5: final MLP ----
    {
        float bm = bm1[l];
        float acc[2] = { bm, bm };
        for (int kc = 0; kc < 51; ++kc) {
            int k = kc * 4;
            float w0 = Wm1[(k + 0) * 64 + l];
            float w1 = Wm1[(k + 1) * 64 + l];
            float w2 = Wm1[(k + 2) * 64 + l];
            float w3 = Wm1[(k + 3) * 64 + l];
#pragma unroll
            for (int e = 0; e < 2; ++e) {
                float4 x = ((const float4*)(S[e] + 256))[kc];
                acc[e] = __builtin_fmaf(x.x, w0, acc[e]);
                acc[e] = __builtin_fmaf(x.y, w1, acc[e]);
                acc[e] = __builtin_fmaf(x.z, w2, acc[e]);
                acc[e] = __builtin_fmaf(x.w, w3, acc[e]);
            }
        }
        float wlast = Wm1[204 * 64 + l];
#pragma unroll
        for (int e = 0; e < 2; ++e) {
            acc[e] = __builtin_fmaf((S[e] + 256)[204], wlast, acc[e]);
            (S[e] + 528)[l] = fmaxf(acc[e], 0.f);
        }
    }
    {
        float bm = bm2[l];
        float acc[2] = { bm, bm };
        for (int kc = 0; kc < 16; ++kc) {
            int k = kc * 4;
            float w0 = Wm2[(k + 0) * 64 + l];
            float w1 = Wm2[(k + 1) * 64 + l];
            float w2 = Wm2[(k + 2) * 64 + l];
            float w3 = Wm2[(k + 3) * 64 + l];
#pragma unroll
            for (int e = 0; e < 2; ++e) {
                float4 x = ((const float4*)(S[e] + 528))[kc];
                acc[e] = __builtin_fmaf(x.x, w0, acc[e]);
                acc[e] = __builtin_fmaf(x.y, w1, acc[e]);
                acc[e] = __builtin_fmaf(x.z, w2, acc[e]);
                acc[e] = __builtin_fmaf(x.w, w3, acc[e]);
            }
        }
#pragma unroll
        for (int e = 0; e < 2; ++e)
            out[(size_t)(b0 + e) * 64 + l] = fmaxf(acc[e], 0.f);
    }
}

extern "C" void kernel_launch(void* const* d_in, const int* in_sizes, int n_in,
                              void* d_out, int out_size, void* d_ws, size_t ws_size,
                              hipStream_t stream) {
    const float* obs  = (const float*)d_in[0];
    const float* W_se = (const float*)d_in[1];
    const float* b_se = (const float*)d_in[2];
    const float* W_de = (const float*)d_in[3];
    const float* b_de = (const float*)d_in[4];
    const float* Wh1  = (const float*)d_in[5];
    const float* ah1  = (const float*)d_in[6];
    const float* Wh2  = (const float*)d_in[7];
    const float* ah2  = (const float*)d_in[8];
    const float* Who  = (const float*)d_in[9];
    const float* aho  = (const float*)d_in[10];
    const float* Wc1  = (const float*)d_in[11];
    const float* ac1  = (const float*)d_in[12];
    const float* Wc2  = (const float*)d_in[13];
    const float* ac2  = (const float*)d_in[14];
    const float* Wco  = (const float*)d_in[15];
    const float* aco  = (const float*)d_in[16];
    const float* Wl1  = (const float*)d_in[17];
    const float* bl1  = (const float*)d_in[18];
    const float* Wl2  = (const float*)d_in[19];
    const float* bl2  = (const float*)d_in[20];
    const float* Wm1  = (const float*)d_in[21];
    const float* bm1  = (const float*)d_in[22];
    const float* Wm2  = (const float*)d_in[23];
    const float* bm2  = (const float*)d_in[24];

    int B = in_sizes[0] / 2064;  // 16384
    pred_kernel<<<B / 4, 128, 0, stream>>>(
        obs, W_se, b_se, W_de, b_de, Wh1, ah1, Wh2, ah2, Who, aho,
        Wc1, ac1, Wc2, ac2, Wco, aco, Wl1, bl1, Wl2, bl2, Wm1, bm1, Wm2, bm2,
        (float*)d_out);
}

// Round 4
// 163.060 us; speedup vs baseline: 1.8277x; 1.8277x over previous
//
#include <hip/hip_runtime.h>

#define DEV __device__ __forceinline__

DEV float wsum64(float v) {
    v += __shfl_xor(v, 32);
    v += __shfl_xor(v, 16);
    v += __shfl_xor(v, 8);
    v += __shfl_xor(v, 4);
    v += __shfl_xor(v, 2);
    v += __shfl_xor(v, 1);
    return v;
}
DEV float wsum16(float v) {
    v += __shfl_xor(v, 8);
    v += __shfl_xor(v, 4);
    v += __shfl_xor(v, 2);
    v += __shfl_xor(v, 1);
    return v;
}
DEV float lrelu(float x, float a) { return x > 0.f ? x : a * x; }
DEV float elu1(float x) { return x > 0.f ? x : (__expf(x) - 1.f); }

// softmax-combine for a 13-node star GAT given per-lane Wh rows.
DEV void star13(const float wh[13], const float* __restrict__ a, int l,
                float& out0, float& wh0) {
    float alo = a[l], ahi = a[64 + l];
    float si0 = wsum64(wh[0] * alo);
    float e[13];
    float m = -1e30f;
#pragma unroll
    for (int r = 0; r < 13; ++r) {
        float sj = wsum64(wh[r] * ahi);
        float t = lrelu(si0 + sj, 0.2f);
        e[r] = t;
        m = fmaxf(m, t);
    }
    float den = 0.f, acc = 0.f;
#pragma unroll
    for (int r = 0; r < 13; ++r) {
        float p = __expf(e[r] - m);
        den += p;
        acc = __builtin_fmaf(p, wh[r], acc);
    }
    out0 = acc / den;
    wh0 = wh[0];
}

DEV void star9(const float wh[9], const float* __restrict__ a, int c,
               float& out0, float& wh0) {
    float alo = a[c], ahi = a[16 + c];
    float si0 = wsum16(wh[0] * alo);
    float e[9];
    float m = -1e30f;
#pragma unroll
    for (int r = 0; r < 9; ++r) {
        float sj = wsum16(wh[r] * ahi);
        float t = lrelu(si0 + sj, 0.2f);
        e[r] = t;
        m = fmaxf(m, t);
    }
    float den = 0.f, acc = 0.f;
#pragma unroll
    for (int r = 0; r < 9; ++r) {
        float p = __expf(e[r] - m);
        den += p;
        acc = __builtin_fmaf(p, wh[r], acc);
    }
    out0 = acc / den;
    wh0 = wh[0];
}

// Output GAT layer: 2 distinct node vectors (hub x0, replicated xr), K mult of 4.
DEV float gatOut(const float* __restrict__ x0, const float* __restrict__ xr, int K4,
                 const float* __restrict__ W, const float* __restrict__ a,
                 float nOth, int l) {
    float w0 = 0.f, wr = 0.f;
    const float4* x04 = (const float4*)x0;
    const float4* xr4 = (const float4*)xr;
    for (int kc = 0; kc < K4; ++kc) {
        float4 xv = x04[kc];
        float4 rv = xr4[kc];
        int k = kc * 4;
        float wk0 = W[(k + 0) * 64 + l];
        float wk1 = W[(k + 1) * 64 + l];
        float wk2 = W[(k + 2) * 64 + l];
        float wk3 = W[(k + 3) * 64 + l];
        w0 = __builtin_fmaf(xv.x, wk0, w0);
        w0 = __builtin_fmaf(xv.y, wk1, w0);
        w0 = __builtin_fmaf(xv.z, wk2, w0);
        w0 = __builtin_fmaf(xv.w, wk3, w0);
        wr = __builtin_fmaf(rv.x, wk0, wr);
        wr = __builtin_fmaf(rv.y, wk1, wr);
        wr = __builtin_fmaf(rv.z, wk2, wr);
        wr = __builtin_fmaf(rv.w, wk3, wr);
    }
    float si0 = wsum64(w0 * a[l]);
    float sj0 = wsum64(w0 * a[64 + l]);
    float sjr = wsum64(wr * a[64 + l]);
    float e0 = lrelu(si0 + sj0, 0.2f);
    float er = lrelu(si0 + sjr, 0.2f);
    float m = fmaxf(e0, er);
    float p0 = __expf(e0 - m);
    float pr = __expf(er - m) * nOth;
    float o0 = (p0 * w0 + pr * wr) / (p0 + pr);
    return (elu1(o0) + nOth * elu1(w0)) * (1.f / (nOth + 1.f));
}

// Per-element LDS region layout (floats), total 1504 (=6016B, 16B aligned):
//  [0..832)    E1 (13x64)        -> after phase2 reused as:
//                x0s[0..128) xrs[128..256) comb[256..464) h1l[464..528)
//                hm[528..592) xc0[592..624) xcr[624..656)
//  [832..1248) hsh (13x32)       -> phase0/1 holds hist (13x16 padded)
//  [1248..1432) curs (184)
//  [1432..1504) hc (9x8 padded)
// Each region is touched by exactly ONE wave -> no __syncthreads anywhere;
// same-wave LDS ordering (in-order DS pipe + compiler lgkmcnt) is sufficient.
#define ELEM_F 1504

__global__ __launch_bounds__(128, 4) void pred_kernel(
    const float* __restrict__ obs,
    const float* __restrict__ W_se, const float* __restrict__ b_se,
    const float* __restrict__ W_de, const float* __restrict__ b_de,
    const float* __restrict__ Wh1, const float* __restrict__ ah1,
    const float* __restrict__ Wh2, const float* __restrict__ ah2,
    const float* __restrict__ Who, const float* __restrict__ aho,
    const float* __restrict__ Wc1, const float* __restrict__ ac1,
    const float* __restrict__ Wc2, const float* __restrict__ ac2,
    const float* __restrict__ Wco, const float* __restrict__ aco,
    const float* __restrict__ Wl1, const float* __restrict__ bl1,
    const float* __restrict__ Wl2, const float* __restrict__ bl2,
    const float* __restrict__ Wm1, const float* __restrict__ bm1,
    const float* __restrict__ Wm2, const float* __restrict__ bm2,
    float* __restrict__ out)
{
    const int l = threadIdx.x & 63;           // lane = channel
    const int w = threadIdx.x >> 6;           // wave in block = element slot
    const int b = blockIdx.x * 2 + w;         // batch element
    const float* o = obs + (size_t)b * 2064;

    __shared__ float lds[2 * ELEM_F];
    float* S    = lds + w * ELEM_F;
    float* E1   = S;                // 13x64
    float* x0s  = S;                // 128
    float* xrs  = S + 128;          // 128
    float* comb = S + 256;          // 208 (205 + pad)
    float* h1l  = S + 464;          // 64
    float* hm   = S + 528;          // 64
    float* xc0  = S + 592;          // 32
    float* xcr  = S + 624;          // 32
    float* H    = S + 832;          // hist 13x16 (then hsh 13x32)
    float* hsh  = S + 832;          // 13x32
    float* curs = S + 1248;         // 184
    float* hc   = S + 1432;         // 9x8

    // ---- phase 0: gather ----
    for (int i = l; i < 208; i += 64) {
        int r = i >> 4, f = i & 15;
        float v = 0.f;
        if (f < 15) {
            int t = f / 3 + 1, ff = f % 3;
            int col = (r == 0) ? (234 + ff) : ((r - 1) * 6 + ff);
            v = o[t * 344 + col];
        }
        H[i] = v;
    }
    for (int i = l; i < 184; i += 64) curs[i] = o[1792 + i];

    // ---- phase 1: 15->64 lrelu(0.1); build cav nodes ----
    {
        float wv[16];
#pragma unroll
        for (int k = 0; k < 15; ++k) wv[k] = W_se[k * 64 + l];
        wv[15] = 0.f;
        float acc[13];
        float bs = b_se[l];
#pragma unroll
        for (int r = 0; r < 13; ++r) acc[r] = bs;
        const float4* H4 = (const float4*)H;
#pragma unroll
        for (int kc = 0; kc < 4; ++kc) {
#pragma unroll
            for (int r = 0; r < 13; ++r) {
                float4 h = H4[r * 4 + kc];
                acc[r] = __builtin_fmaf(h.x, wv[kc * 4 + 0], acc[r]);
                acc[r] = __builtin_fmaf(h.y, wv[kc * 4 + 1], acc[r]);
                acc[r] = __builtin_fmaf(h.z, wv[kc * 4 + 2], acc[r]);
                acc[r] = __builtin_fmaf(h.w, wv[kc * 4 + 3], acc[r]);
            }
        }
#pragma unroll
        for (int r = 0; r < 13; ++r) E1[r * 64 + l] = lrelu(acc[r], 0.1f);
    }
    if (l < 54) {
        int r = l / 6, f = l % 6;
        float v;
        if (r == 0) {
            int idx = (f < 3) ? (162 + f) : ((f == 3) ? 181 : (175 + f));
            v = curs[idx];
        } else {
            v = curs[(r - 1) * 6 + f];
        }
        hc[r * 8 + f] = v;
    }

    // ---- phase 2: 64->32 linear -> hsh ----
    {
        int c = l & 31, r0 = l >> 5;
        float acc[7];
        float bd = b_de[c];
#pragma unroll
        for (int i = 0; i < 7; ++i) acc[i] = bd;
        const float4* E4 = (const float4*)E1;
        for (int kc = 0; kc < 16; ++kc) {
            int k = kc * 4;
            float w0 = W_de[(k + 0) * 32 + c];
            float w1 = W_de[(k + 1) * 32 + c];
            float w2 = W_de[(k + 2) * 32 + c];
            float w3 = W_de[(k + 3) * 32 + c];
#pragma unroll
            for (int i = 0; i < 7; ++i) {
                int r = r0 + 2 * i;
                float4 e = E4[(r < 13 ? r : 0) * 16 + kc];
                acc[i] = __builtin_fmaf(e.x, w0, acc[i]);
                acc[i] = __builtin_fmaf(e.y, w1, acc[i]);
                acc[i] = __builtin_fmaf(e.z, w2, acc[i]);
                acc[i] = __builtin_fmaf(e.w, w3, acc[i]);
            }
        }
#pragma unroll
        for (int i = 0; i < 7; ++i) {
            int r = r0 + 2 * i;
            if (r < 13) hsh[r * 32 + c] = acc[i];
        }
    }

    // ---- phase 3: fused gat13 pair, gat9 pair, lanes1, road gather ----
    {
        float wh1[13], wh2[13];
#pragma unroll
        for (int r = 0; r < 13; ++r) { wh1[r] = 0.f; wh2[r] = 0.f; }
        const float4* hs4 = (const float4*)hsh;
#pragma unroll
        for (int kc = 0; kc < 8; ++kc) {
            int k = kc * 4;
            float a0 = Wh1[(k + 0) * 64 + l], b0 = Wh2[(k + 0) * 64 + l];
            float a1 = Wh1[(k + 1) * 64 + l], b1 = Wh2[(k + 1) * 64 + l];
            float a2 = Wh1[(k + 2) * 64 + l], b2 = Wh2[(k + 2) * 64 + l];
            float a3 = Wh1[(k + 3) * 64 + l], b3 = Wh2[(k + 3) * 64 + l];
#pragma unroll
            for (int r = 0; r < 13; ++r) {
                float4 h = hs4[r * 8 + kc];
                wh1[r] = __builtin_fmaf(h.x, a0, wh1[r]);
                wh1[r] = __builtin_fmaf(h.y, a1, wh1[r]);
                wh1[r] = __builtin_fmaf(h.z, a2, wh1[r]);
                wh1[r] = __builtin_fmaf(h.w, a3, wh1[r]);
                wh2[r] = __builtin_fmaf(h.x, b0, wh2[r]);
                wh2[r] = __builtin_fmaf(h.y, b1, wh2[r]);
                wh2[r] = __builtin_fmaf(h.z, b2, wh2[r]);
                wh2[r] = __builtin_fmaf(h.w, b3, wh2[r]);
            }
        }
        float o1, r1, o2, r2;
        star13(wh1, ah1, l, o1, r1);
        star13(wh2, ah2, l, o2, r2);
        x0s[l] = o1; x0s[64 + l] = o2;
        xrs[l] = r1; xrs[64 + l] = r2;
    }
    {
        int c = l & 15;
        float wc1[9], wc2[9];
#pragma unroll
        for (int r = 0; r < 9; ++r) { wc1[r] = 0.f; wc2[r] = 0.f; }
#pragma unroll
        for (int k = 0; k < 6; ++k) {
            float w1 = Wc1[k * 16 + c];
            float w2 = Wc2[k * 16 + c];
#pragma unroll
            for (int r = 0; r < 9; ++r) {
                float h = hc[r * 8 + k];
                wc1[r] = __builtin_fmaf(h, w1, wc1[r]);
                wc2[r] = __builtin_fmaf(h, w2, wc2[r]);
            }
        }
        float o1, r1, o2, r2;
        star9(wc1, ac1, c, o1, r1);
        star9(wc2, ac2, c, o2, r2);
        if (l < 16) {
            xc0[l] = o1; xc0[16 + l] = o2;
            xcr[l] = r1; xcr[16 + l] = r2;
        }
    }
    {
        float acc = bl1[l];
        const float4* C4 = (const float4*)(curs + 48);
        for (int kc = 0; kc < 27; ++kc) {
            float4 x = C4[kc];
            int k = kc * 4;
            acc = __builtin_fmaf(x.x, Wl1[(k + 0) * 64 + l], acc);
            acc = __builtin_fmaf(x.y, Wl1[(k + 1) * 64 + l], acc);
            acc = __builtin_fmaf(x.z, Wl1[(k + 2) * 64 + l], acc);
            acc = __builtin_fmaf(x.w, Wl1[(k + 3) * 64 + l], acc);
        }
        h1l[l] = fmaxf(acc, 0.f);
    }
    if (l < 16) {
        float v = 0.f;
        if (l < 13) {
            int idx;
            if (l < 10) {
                int p = l >> 1, odd = l & 1;
                idx = ((p & 1) ? 175 : 156) + (p >> 1) * 2 + odd;
            } else {
                idx = 169 + l; // 179,180,181
            }
            v = curs[idx];
        }
        comb[192 + l] = v;   // pads comb[205..207] with 0
    }

    // ---- phase 4: GAT output layers + lanes2 ----
    float cv0 = gatOut(x0s, xrs, 32, Who, aho, 12.f, l);
    float cv1 = gatOut(xc0, xcr, 8,  Wco, aco, 8.f,  l);
    float cv2;
    {
        float acc = bl2[l];
        const float4* H4 = (const float4*)h1l;
        for (int kc = 0; kc < 16; ++kc) {
            float4 x = H4[kc];
            int k = kc * 4;
            acc = __builtin_fmaf(x.x, Wl2[(k + 0) * 64 + l], acc);
            acc = __builtin_fmaf(x.y, Wl2[(k + 1) * 64 + l], acc);
            acc = __builtin_fmaf(x.z, Wl2[(k + 2) * 64 + l], acc);
            acc = __builtin_fmaf(x.w, Wl2[(k + 3) * 64 + l], acc);
        }
        cv2 = fmaxf(acc, 0.f);
    }
    comb[l] = cv0;
    comb[64 + l] = cv1;
    comb[128 + l] = cv2;

    // ---- phase 5: final MLP ----
    {
        float acc = bm1[l];
        const float4* C4 = (const float4*)comb;
        for (int kc = 0; kc < 51; ++kc) {
            float4 x = C4[kc];
            int k = kc * 4;
            acc = __builtin_fmaf(x.x, Wm1[(k + 0) * 64 + l], acc);
            acc = __builtin_fmaf(x.y, Wm1[(k + 1) * 64 + l], acc);
            acc = __builtin_fmaf(x.z, Wm1[(k + 2) * 64 + l], acc);
            acc = __builtin_fmaf(x.w, Wm1[(k + 3) * 64 + l], acc);
        }
        acc = __builtin_fmaf(comb[204], Wm1[204 * 64 + l], acc);
        hm[l] = fmaxf(acc, 0.f);
    }
    {
        float acc = bm2[l];
        const float4* H4 = (const float4*)hm;
        for (int kc = 0; kc < 16; ++kc) {
            float4 x = H4[kc];
            int k = kc * 4;
            acc = __builtin_fmaf(x.x, Wm2[(k + 0) * 64 + l], acc);
            acc = __builtin_fmaf(x.y, Wm2[(k + 1) * 64 + l], acc);
            acc = __builtin_fmaf(x.z, Wm2[(k + 2) * 64 + l], acc);
            acc = __builtin_fmaf(x.w, Wm2[(k + 3) * 64 + l], acc);
        }
        out[(size_t)b * 64 + l] = fmaxf(acc, 0.f);
    }
}

extern "C" void kernel_launch(void* const* d_in, const int* in_sizes, int n_in,
                              void* d_out, int out_size, void* d_ws, size_t ws_size,
                              hipStream_t stream) {
    const float* obs  = (const float*)d_in[0];
    const float* W_se = (const float*)d_in[1];
    const float* b_se = (const float*)d_in[2];
    const float* W_de = (const float*)d_in[3];
    const float* b_de = (const float*)d_in[4];
    const float* Wh1  = (const float*)d_in[5];
    const float* ah1  = (const float*)d_in[6];
    const float* Wh2  = (const float*)d_in[7];
    const float* ah2  = (const float*)d_in[8];
    const float* Who  = (const float*)d_in[9];
    const float* aho  = (const float*)d_in[10];
    const float* Wc1  = (const float*)d_in[11];
    const float* ac1  = (const float*)d_in[12];
    const float* Wc2  = (const float*)d_in[13];
    const float* ac2  = (const float*)d_in[14];
    const float* Wco  = (const float*)d_in[15];
    const float* aco  = (const float*)d_in[16];
    const float* Wl1  = (const float*)d_in[17];
    const float* bl1  = (const float*)d_in[18];
    const float* Wl2  = (const float*)d_in[19];
    const float* bl2  = (const float*)d_in[20];
    const float* Wm1  = (const float*)d_in[21];
    const float* bm1  = (const float*)d_in[22];
    const float* Wm2  = (const float*)d_in[23];
    const float* bm2  = (const float*)d_in[24];

    int B = in_sizes[0] / 2064;  // 16384
    pred_kernel<<<B / 2, 128, 0, stream>>>(
        obs, W_se, b_se, W_de, b_de, Wh1, ah1, Wh2, ah2, Who, aho,
        Wc1, ac1, Wc2, ac2, Wco, aco, Wl1, bl1, Wl2, bl2, Wm1, bm1, Wm2, bm2,
        (float*)d_out);
}